// Round 1
// baseline (131.531 us; speedup 1.0000x reference)
//
#include <hip/hip_runtime.h>
#include <math.h>

// SOR defense: B=4, K=8192, 3D points. k-NN with k=2 (3 smallest incl. self).
// Outputs: masked_pc [4,8192,3] (98304 floats) then mask [4,8192] (32768 floats).

constexpr int B = 4;
constexpr int K = 8192;
constexpr int QPB = 256;      // queries per block (= threads)
constexpr int HALF = 4096;    // j-range per block (2 halves)

#define BIG 3.0e38f

// Branchless insert of d into sorted top-3 (d0<=d1<=d2 smallest seen).
#define INSERT3(d, d0, d1, d2)          \
  do {                                  \
    float e_ = fminf((d), (d2));        \
    (d2) = fmaxf((d1), e_);             \
    float m_ = fminf((d1), e_);         \
    (d1) = fmaxf((d0), m_);             \
    (d0) = fminf((d0), m_);             \
  } while (0)

__global__ __launch_bounds__(QPB) void knn_part_kernel(
    const float* __restrict__ x, float* __restrict__ part) {
  const int bid  = blockIdx.x;
  const int half = bid & 1;
  const int kc   = (bid >> 1) & 31;
  const int b    = bid >> 6;
  const int tid  = threadIdx.x;
  const int k    = kc * QPB + tid;

  const float* xb = x + (size_t)b * K * 3;

  // Query point + its squared norm (same op order as reference: (x*x+y*y)+z*z)
  const float qx = xb[(size_t)k * 3 + 0];
  const float qy = xb[(size_t)k * 3 + 1];
  const float qz = xb[(size_t)k * 3 + 2];
  const float xxk = (qx * qx + qy * qy) + qz * qz;

  __shared__ float4 s[HALF];  // 64 KiB: (x, y, z, ||p||^2)

  const int jbase = half * HALF;
  for (int i = tid; i < HALF; i += QPB) {
    const float px = xb[(size_t)(jbase + i) * 3 + 0];
    const float py = xb[(size_t)(jbase + i) * 3 + 1];
    const float pz = xb[(size_t)(jbase + i) * 3 + 2];
    s[i] = make_float4(px, py, pz, (px * px + py * py) + pz * pz);
  }
  __syncthreads();

  float d0 = BIG, d1 = BIG, d2 = BIG;
#pragma unroll 8
  for (int j = 0; j < HALF; ++j) {
    const float4 p = s[j];
    const float dot = (qx * p.x + qy * p.y) + qz * p.z;
    const float d = (xxk - 2.0f * dot) + p.w;
    INSERT3(d, d0, d1, d2);
  }

  float* pp = part + ((size_t)(b * K + k) * 2 + half) * 3;
  pp[0] = d0;
  pp[1] = d1;
  pp[2] = d2;
}

__global__ __launch_bounds__(1024) void finalize_kernel(
    const float* __restrict__ x, const float* __restrict__ part,
    float* __restrict__ out) {
  const int b = blockIdx.x;
  const int tid = threadIdx.x;
  constexpr int PER = K / 1024;  // 8

  float val[PER];
  double s = 0.0, s2 = 0.0;

  for (int i = 0; i < PER; ++i) {
    const int k = i * 1024 + tid;
    const float* pp = part + (size_t)(b * K + k) * 6;
    float d0 = BIG, d1 = BIG, d2 = BIG;
#pragma unroll
    for (int t = 0; t < 6; ++t) {
      const float d = pp[t];
      INSERT3(d, d0, d1, d2);
    }
    // drop self (d0 ~ 0), mean of 2nd and 3rd smallest
    const float v = 0.5f * (d1 + d2);
    val[i] = v;
    s += (double)v;
    s2 += (double)v * (double)v;
  }

  // wave (64-lane) reduction
  for (int off = 32; off > 0; off >>= 1) {
    s  += __shfl_down(s, off, 64);
    s2 += __shfl_down(s2, off, 64);
  }

  __shared__ double rs[16], rs2[16];
  __shared__ float sthr;
  const int wave = tid >> 6;
  const int lane = tid & 63;
  if (lane == 0) { rs[wave] = s; rs2[wave] = s2; }
  __syncthreads();
  if (tid == 0) {
    double S = 0.0, S2 = 0.0;
    for (int w = 0; w < 16; ++w) { S += rs[w]; S2 += rs2[w]; }
    const double mean = S / (double)K;
    const double var  = (S2 - S * S / (double)K) / (double)(K - 1);
    const double thr  = mean + 1.1 * sqrt(var);
    sthr = (float)thr;
  }
  __syncthreads();

  const float thr = sthr;
  for (int i = 0; i < PER; ++i) {
    const int k = i * 1024 + tid;
    const float m = (val[i] <= thr) ? 1.0f : 0.0f;
    out[(size_t)B * K * 3 + (size_t)b * K + k] = m;
    const size_t base = (size_t)(b * K + k) * 3;
    out[base + 0] = x[base + 0] * m;
    out[base + 1] = x[base + 1] * m;
    out[base + 2] = x[base + 2] * m;
  }
}

extern "C" void kernel_launch(void* const* d_in, const int* in_sizes, int n_in,
                              void* d_out, int out_size, void* d_ws, size_t ws_size,
                              hipStream_t stream) {
  const float* x = (const float*)d_in[0];
  float* out = (float*)d_out;
  float* part = (float*)d_ws;  // [B*K][2][3] floats = 768 KiB

  knn_part_kernel<<<B * 32 * 2, QPB, 0, stream>>>(x, part);
  finalize_kernel<<<B, 1024, 0, stream>>>(x, part, out);
}